// Round 4
// baseline (730.962 us; speedup 1.0000x reference)
//
#include <hip/hip_runtime.h>

#define N_  8
#define C_  32
#define H_  224
#define W_  224
#define TM_ 4
#define TA  32   // output tile extent along a (rows)
#define TB  32   // output tile extent along b (cols)

typedef float fx4 __attribute__((ext_vector_type(4)));  // clang vector for nontemporal builtin

// Block = 256 threads handles one (c, 32x32 output tile) for ALL t (4) and n (8).
// Loop order: n OUTERMOST, t inner. For a fixed (block, n) the 4 t-warps sample
// nearly the same ~10 KB input window (warps = identity + 0.05*noise), so t=0
// fetches it and t=1..3 hit L1/L2. Geometry is recomputed per n (VALU has 6x
// headroom at 14% busy); this keeps VGPRs low (no 48-reg hoisted state).
// Output is written with nontemporal float4 stores so the 211 MB write stream
// does not evict the cached input planes.
// Compute phase: lanes along a -> sample x consecutive per lane -> coalesced gathers.
// Write  phase: lanes along b -> coalesced float4 stores (via LDS transpose tile).
// Reference quirk preserved: hx = xs[a], hy = ys[b]; out channel = c*TM + t.
__global__ __launch_bounds__(256, 8) void persp_kernel(
    const float* __restrict__ inp,   // (N, C, H, W)
    const float* __restrict__ wt,    // (TM, C, 8)
    float* __restrict__ out)         // (N, C*TM, H, W)
{
    __shared__ float tile[TM_][TA][TB + 1];   // 16896 B -> 8 blocks/CU

    const int tid = threadIdx.x;
    const int c   = blockIdx.y;
    const int ta  = blockIdx.x / (W_ / TB);
    const int tb  = blockIdx.x % (W_ / TB);
    const int a0  = ta * TA;
    const int b0  = tb * TB;

    // compute-phase mapping: lane -> a, group -> b
    const int a_off = tid & 31;        // 0..31 along a (fast, per half-wave)
    const int bgrp  = tid >> 5;        // 0..7
    const int a     = a0 + a_off;

    const float step = 2.0f / 223.0f;  // linspace(-1,1,224) step
    const float hx   = -1.0f + (float)a * step;   // xs[a]

    // write-phase mapping: lane -> 4 consecutive b (float4), group -> a rows
    const int j4 = (tid & 7) * 4;      // 0,4,...,28 along b
    const int iw = tid >> 3;           // 0..31 along a

    const size_t plane   = (size_t)H_ * W_;
    const size_t istride = (size_t)C_ * plane;         // per-n input stride
    const size_t ostride = (size_t)(C_ * TM_) * plane; // per-n output stride

    // theta for all 4 t: uniform per block -> lands in SGPRs
    float th[TM_][8];
#pragma unroll
    for (int t = 0; t < TM_; ++t)
#pragma unroll
        for (int k = 0; k < 8; ++k)
            th[t][k] = wt[((size_t)t * C_ + c) * 8 + k];

    const float* ibase = inp + (size_t)c * plane;
    float* obase = out + ((size_t)c * TM_) * plane + (size_t)(a0 + iw) * W_ + (b0 + j4);

    for (int n = 0; n < N_; ++n) {
        const float* ib = ibase + (size_t)n * istride;

#pragma unroll
        for (int t = 0; t < TM_; ++t) {
#pragma unroll
            for (int p = 0; p < 4; ++p) {
                const int b = b0 + bgrp + 8 * p;
                const float hy = -1.0f + (float)b * step;  // ys[b]

                const float w0 = th[t][0] * hx + th[t][1] * hy + th[t][2];
                const float w1 = th[t][3] * hx + th[t][4] * hy + th[t][5];
                const float w2 = th[t][6] * hx + th[t][7] * hy + 1.0f;

                const float rw = 1.0f / w2;           // one divide, two muls
                const float xs = w0 * rw;
                const float ys = w1 * rw;

                const float x = 0.5f * ((xs + 1.0f) * 222.0f);
                const float y = 0.5f * ((ys + 1.0f) * 222.0f);

                int x0i = (int)floorf(x);
                int y0i = (int)floorf(y);
                int x1i = x0i + 1;
                int y1i = y0i + 1;
                x0i = min(max(x0i, 0), W_ - 1);
                x1i = min(max(x1i, 0), W_ - 1);
                y0i = min(max(y0i, 0), H_ - 1);
                y1i = min(max(y1i, 0), H_ - 1);

                const float x0f = (float)x0i, x1f = (float)x1i;
                const float y0f = (float)y0i, y1f = (float)y1i;

                const float wa = (x1f - x) * (y1f - y);
                const float wb = (x1f - x) * (y1f - y0f);
                const float wc = (x - x0f) * (y1f - y);
                const float wd = (x - x0f) * (y - y0f);

                const int iA = y0i * W_ + x0i;
                const int iB = y1i * W_ + x0i;
                const int iC = y0i * W_ + x1i;
                const int iD = y1i * W_ + x1i;

                const float Ia = ib[iA];
                const float Ib = ib[iB];
                const float Ic = ib[iC];
                const float Id = ib[iD];

                tile[t][a_off][bgrp + 8 * p] =
                    wa * Ia + wb * Ib + wc * Ic + wd * Id;
            }
        }
        __syncthreads();

        // coalesced nontemporal float4 write-out: lanes along b
        float* on = obase + (size_t)n * ostride;
#pragma unroll
        for (int t = 0; t < TM_; ++t) {
            fx4 v;
            v.x = tile[t][iw][j4 + 0];
            v.y = tile[t][iw][j4 + 1];
            v.z = tile[t][iw][j4 + 2];
            v.w = tile[t][iw][j4 + 3];
            __builtin_nontemporal_store(
                v, reinterpret_cast<fx4*>(on + (size_t)t * plane));
        }
        __syncthreads();
    }
}

extern "C" void kernel_launch(void* const* d_in, const int* in_sizes, int n_in,
                              void* d_out, int out_size, void* d_ws, size_t ws_size,
                              hipStream_t stream) {
    const float* inp = (const float*)d_in[0];   // (8,32,224,224) f32
    const float* wt  = (const float*)d_in[1];   // (4,32,8) f32
    float* out = (float*)d_out;                 // (8,128,224,224) f32

    dim3 grid((H_ / TA) * (W_ / TB), C_);       // 49 x 32 = 1568 blocks
    persp_kernel<<<grid, 256, 0, stream>>>(inp, wt, out);
}